// Round 20
// baseline (84.014 us; speedup 1.0000x reference)
//
#include <hip/hip_runtime.h>
#include <hip/hip_bf16.h>
#include <hip/hip_cooperative_groups.h>

namespace cg = cooperative_groups;

#define N_NODES   200000
#define N_PATCHES 256
#define TSTEPS    12
#define NHID      16
#define HORIZON   12
#define GDIM      192            // NHID * TSTEPS
#define IN_DIM    204            // GDIM + TSTEPS
#define NCHUNKS   6250           // N_NODES / 32 (exact)
#define K2_THREADS 512
#define TOTAL_WAVES 2048         // 256 blocks x 8 waves

// Tiled PH layout: row = patch p, 464 B (29 uint4). Slot (t, hi, G) = 8 B
// (4 bf16) holding cols t*32 + 8G + 4hi + {0..3}; offset (t*8+hi*4+G)*8 B.
#define TROW_U16  232            // u16 per row (464 B)
#define TROW_U4   29             // uint4 per row
#define TBL_U4    7424           // 256 * 29

typedef __attribute__((ext_vector_type(8)))  short        bf16x8;
typedef __attribute__((ext_vector_type(16))) float        f32x16;
typedef __attribute__((ext_vector_type(4)))  unsigned int u32x4;

// cold-path pack: software RNE
__device__ __forceinline__ unsigned int pk2(float lo, float hi) {
    unsigned short l = __builtin_bit_cast(unsigned short, __float2bfloat16(lo));
    unsigned short h = __builtin_bit_cast(unsigned short, __float2bfloat16(hi));
    return ((unsigned int)h << 16) | (unsigned int)l;
}

// hot-path pack: single HW instruction (RNE, bit-identical to pk2)
__device__ __forceinline__ unsigned int cvtpk(float lo, float hi) {
    unsigned int r;
    asm("v_cvt_pk_bf16_f32 %0, %1, %2" : "=v"(r) : "v"(lo), "v"(hi));
    return r;
}

__device__ __forceinline__ bf16x8 frag_of(unsigned int a, unsigned int b,
                                          unsigned int c, unsigned int d) {
    u32x4 u; u[0] = a; u[1] = b; u[2] = c; u[3] = d;
    return __builtin_bit_cast(bf16x8, u);
}

__device__ __forceinline__ float bf16bits_lo(unsigned int w) {
    return __builtin_bit_cast(float, w << 16);
}
__device__ __forceinline__ float bf16bits_hi(unsigned int w) {
    return __builtin_bit_cast(float, w & 0xffff0000u);
}

// async global->LDS copy, 16B per lane (wave-uniform base + lane*16 dest)
__device__ __forceinline__ void gload_lds16(const uint4* g, uint4* l) {
    __builtin_amdgcn_global_load_lds(
        (const __attribute__((address_space(1))) unsigned int*)g,
        (__attribute__((address_space(3))) unsigned int*)l,
        16, 0, 0);
}

// Clamped weight fetch helpers (OOB -> 0)
__device__ __forceinline__ float ldW1f(const float* __restrict__ W1, int k, int j) {
    const bool ok = (k < TSTEPS) && (j < IN_DIM);
    const int  idx = ok ? ((GDIM + k) * IN_DIM + j) : 0;
    const float v = W1[idx];
    return ok ? v : 0.0f;
}
__device__ __forceinline__ float ldW2t(const float* __restrict__ W2, int j, int o) {
    const bool ok = (j < IN_DIM) && (o < HORIZON);
    const int  idx = ok ? (j * HORIZON + o) : 0;
    const float v = W2[idx];
    return ok ? v : 0.0f;
}

// col j -> u16 index within a tiled row
__device__ __forceinline__ int tiled_idx(int j) {
    const int t = j >> 5, w = j & 31;
    const int G = w >> 3, hb = (w >> 2) & 1, q = w & 3;
    return ((t * 8 + hb * 4 + G) << 2) + q;
}

// ---------------------------------------------------------------------------
// SINGLE cooperative kernel (grid 256 x 512, 118784 B LDS, 1 block/CU).
// Phase A: block b computes patch b's PH row (fp32, 2-way i-split via LDS)
//          -> global patch_t (tiled bf16); block 0 also packs wfrag.
// __threadfence + grid.sync().
// Phase B: EXACT R18 body — async-stage tiled table to LDS, then per-wave
//          MFMA chunk loop (cvtpk packs, ping-pong C-init, even/odd accs).
// Eliminates one kernel dispatch + inter-kernel drain from the graph.
// ---------------------------------------------------------------------------
__global__ __launch_bounds__(K2_THREADS) void fused_mlp(
    const float* __restrict__ mixer_x,        // (1,12,256,16)
    const float* __restrict__ features,       // (200000,12)
    const float* __restrict__ W1,             // (204,204)
    const float* __restrict__ b1,             // (204)
    const float* __restrict__ W2,             // (204,12)
    const float* __restrict__ b2,             // (12)
    const int*   __restrict__ node_patch,     // (200000)
    unsigned short* __restrict__ patch_t,     // ws: (256,232) bf16 tiled
    u32x4* __restrict__ wfrag,                // ws: (20,64)
    float* __restrict__ out)                  // (200000,12)
{
    __shared__ unsigned short smem[N_PATCHES * TROW_U16];   // 118784 B

    const int tid  = threadIdx.x;
    const int lane = tid & 63;
    const int wid  = tid >> 6;
    const int jl   = lane & 31;
    const int hi   = lane >> 5;
    const int hi2  = hi * 2;

    // ---- first chunk's loads: issue first, hide under phase A -------------
    int c = blockIdx.x * 8 + wid;                         // 0..2047
    float4 fa, fb, fc; int p;
    {
        const float4* fp = (const float4*)(features + (c * 32 + jl) * TSTEPS);
        fa = fp[0]; fb = fp[1]; fc = fp[2];
        p  = node_patch[c * 32 + jl];
    }
    const float4 b2A = *(const float4*)(b2 + 4 * hi);     // b2[0..3] / b2[4..7]
    const float4 b2B = *(const float4*)(b2 + 8);          // b2[8..11] (hi0)

    // ---- Phase A: this block computes patch blockIdx.x --------------------
    {
        float* xsf  = (float*)smem;           // 192 floats (768 B)
        float* part = (float*)smem + 192;     // 204 floats
        const int pa = blockIdx.x;
        const int j  = tid & 255;
        const int q  = tid >> 8;              // i-half 0/1 (96 i each)

        if (tid < GDIM) {
            const int t = tid >> 4, f = tid & 15;
            xsf[tid] = mixer_x[(t * N_PATCHES + pa) * NHID + f];
        }
        __syncthreads();

        float acc = 0.0f;
        if (j < IN_DIM) {
            acc = (q == 0) ? b1[j] : 0.0f;
            const int ibase = q * 96;
#pragma unroll 16
            for (int i = 0; i < 96; ++i)
                acc = fmaf(xsf[ibase + i], W1[(ibase + i) * IN_DIM + j], acc);
            if (q) part[j] = acc;
        }
        __syncthreads();

        if (q == 0) {
            if (j < IN_DIM) {
                const float v = acc + part[j];
                patch_t[pa * TROW_U16 + tiled_idx(j)] =
                    __builtin_bit_cast(unsigned short, __float2bfloat16(v));
            } else if (j < 224) {
                patch_t[pa * TROW_U16 + tiled_idx(j)] = 0;  // pad cols zeroed
            }
        }

        if (blockIdx.x == 0) {                // wfrag pack (stacked k-layout)
            const int kb = 4 * hi;
            for (int f = wid; f < 20; f += 8) {
                u32x4 u;
                if (f < 7) {
                    const int j2 = f * 32 + jl;
                    u[0] = pk2(ldW1f(W1, kb + 0,  j2), ldW1f(W1, kb + 1,  j2));
                    u[1] = pk2(ldW1f(W1, kb + 2,  j2), ldW1f(W1, kb + 3,  j2));
                    u[2] = pk2(ldW1f(W1, kb + 8,  j2), ldW1f(W1, kb + 9,  j2));
                    u[3] = pk2(ldW1f(W1, kb + 10, j2), ldW1f(W1, kb + 11, j2));
                } else {
                    const int j0 = (f - 7) * 16 + kb;
                    u[0] = pk2(ldW2t(W2, j0 + 0,  jl), ldW2t(W2, j0 + 1,  jl));
                    u[1] = pk2(ldW2t(W2, j0 + 2,  jl), ldW2t(W2, j0 + 3,  jl));
                    u[2] = pk2(ldW2t(W2, j0 + 8,  jl), ldW2t(W2, j0 + 9,  jl));
                    u[3] = pk2(ldW2t(W2, j0 + 10, jl), ldW2t(W2, j0 + 11, jl));
                }
                wfrag[f * 64 + lane] = u;
            }
        }
    }

    __threadfence();                          // device-scope release
    cg::this_grid().sync();                   // all PH rows + wfrag visible

    // ---- Phase B: R18 body -------------------------------------------------
    bf16x8 A1f[7], A2f[13];
#pragma unroll
    for (int f = 0; f < 7; ++f)
        A1f[f] = __builtin_bit_cast(bf16x8, wfrag[f * 64 + lane]);
#pragma unroll
    for (int f = 0; f < 13; ++f)
        A2f[f] = __builtin_bit_cast(bf16x8, wfrag[(7 + f) * 64 + lane]);

    // async stage tiled bf16 patch table -> LDS
    {
        const uint4* src = (const uint4*)patch_t;
        uint4* dst = (uint4*)smem;
#pragma unroll
        for (int k = 0; k < 15; ++k) {
            const int i = tid + k * K2_THREADS;
            if (i < TBL_U4) gload_lds16(src + i, dst + i);
        }
    }
    __syncthreads();   // drains vmcnt (incl. global_load_lds) + lgkm

    const uint4* ph4 = (const uint4*)smem;

    while (true) {
        const int  cn    = c + TOTAL_WAVES;
        const bool haveN = (cn < NCHUNKS);
        float4 fa2, fb2, fc2; int p2 = 0;
        if (haveN) {                                      // prefetch next chunk
            const float4* fq = (const float4*)(features + (cn * 32 + jl) * TSTEPS);
            fa2 = fq[0]; fb2 = fq[1]; fc2 = fq[2];
            p2  = node_patch[cn * 32 + jl];
        }

        // B1: F^T[k][node], stacked layout (k>=12 -> 0), HW pack
        const bf16x8 B1 = frag_of(hi ? cvtpk(fb.x, fb.y) : cvtpk(fa.x, fa.y),
                                  hi ? cvtpk(fb.z, fb.w) : cvtpk(fa.z, fa.w),
                                  hi ? 0u                : cvtpk(fc.x, fc.y),
                                  hi ? 0u                : cvtpk(fc.z, fc.w));

        const int pbase = p * TROW_U4 + hi2;

        f32x16 oE, oO;
#pragma unroll
        for (int e = 0; e < 16; ++e) { oE[e] = 0.0f; oO[e] = 0.0f; }

        // ping-pong C-init prefetch (2 x b128 per tile)
        uint4 nxa[2], nxb[2];
        nxa[0] = ph4[pbase];
        nxb[0] = ph4[pbase + 1];

#pragma unroll
        for (int t = 0; t < 7; ++t) {
            const uint4 ra = nxa[t & 1];
            const uint4 rb = nxb[t & 1];
            if (t < 6) {                                  // prefetch tile t+1
                nxa[(t + 1) & 1] = ph4[pbase + (t + 1) * 4];
                nxb[(t + 1) & 1] = ph4[pbase + (t + 1) * 4 + 1];
            }

            f32x16 acc;
            acc[0]  = bf16bits_lo(ra.x); acc[1]  = bf16bits_hi(ra.x);
            acc[2]  = bf16bits_lo(ra.y); acc[3]  = bf16bits_hi(ra.y);
            acc[4]  = bf16bits_lo(ra.z); acc[5]  = bf16bits_hi(ra.z);
            acc[6]  = bf16bits_lo(ra.w); acc[7]  = bf16bits_hi(ra.w);
            acc[8]  = bf16bits_lo(rb.x); acc[9]  = bf16bits_hi(rb.x);
            acc[10] = bf16bits_lo(rb.y); acc[11] = bf16bits_hi(rb.y);
            acc[12] = bf16bits_lo(rb.z); acc[13] = bf16bits_hi(rb.z);
            acc[14] = bf16bits_lo(rb.w); acc[15] = bf16bits_hi(rb.w);

            acc = __builtin_amdgcn_mfma_f32_32x32x16_bf16(A1f[t], B1, acc, 0, 0, 0);

            // relu + HW pack: acc element order IS the B-operand element order
            const bf16x8 ba = frag_of(
                cvtpk(fmaxf(acc[0], 0.f), fmaxf(acc[1], 0.f)),
                cvtpk(fmaxf(acc[2], 0.f), fmaxf(acc[3], 0.f)),
                cvtpk(fmaxf(acc[4], 0.f), fmaxf(acc[5], 0.f)),
                cvtpk(fmaxf(acc[6], 0.f), fmaxf(acc[7], 0.f)));
            oE = __builtin_amdgcn_mfma_f32_32x32x16_bf16(A2f[2 * t], ba, oE, 0, 0, 0);

            if (t < 6) {
                const bf16x8 bb = frag_of(
                    cvtpk(fmaxf(acc[8],  0.f), fmaxf(acc[9],  0.f)),
                    cvtpk(fmaxf(acc[10], 0.f), fmaxf(acc[11], 0.f)),
                    cvtpk(fmaxf(acc[12], 0.f), fmaxf(acc[13], 0.f)),
                    cvtpk(fmaxf(acc[14], 0.f), fmaxf(acc[15], 0.f)));
                oO = __builtin_amdgcn_mfma_f32_32x32x16_bf16(A2f[2 * t + 1], bb, oO, 0, 0, 0);
            }
        }

        // ---- store: D row of elem e = (e&3)+8*(e>>2)+4*hi, col = node -----
        {
            const int node = c * 32 + jl;                 // always < N_NODES
            float* orow = out + node * HORIZON;
            const float s0 = oE[0] + oO[0], s1 = oE[1] + oO[1];
            const float s2 = oE[2] + oO[2], s3 = oE[3] + oO[3];
            if (hi == 0) {
                const float s4 = oE[4] + oO[4], s5 = oE[5] + oO[5];
                const float s6 = oE[6] + oO[6], s7 = oE[7] + oO[7];
                *(float4*)(orow + 0) = make_float4(s0 + b2A.x, s1 + b2A.y,
                                                   s2 + b2A.z, s3 + b2A.w);
                *(float4*)(orow + 8) = make_float4(s4 + b2B.x, s5 + b2B.y,
                                                   s6 + b2B.z, s7 + b2B.w);
            } else {
                *(float4*)(orow + 4) = make_float4(s0 + b2A.x, s1 + b2A.y,
                                                   s2 + b2A.z, s3 + b2A.w);
            }
        }

        if (!haveN) break;
        fa = fa2; fb = fb2; fc = fc2; p = p2; c = cn;
    }
}

// ---------------------------------------------------------------------------
extern "C" void kernel_launch(void* const* d_in, const int* in_sizes, int n_in,
                              void* d_out, int out_size, void* d_ws, size_t ws_size,
                              hipStream_t stream) {
    const float* mixer_x    = (const float*)d_in[0];
    const float* features   = (const float*)d_in[1];
    const float* W1         = (const float*)d_in[2];
    const float* b1         = (const float*)d_in[3];
    const float* W2         = (const float*)d_in[4];
    const float* b2         = (const float*)d_in[5];
    const int*   node_patch = (const int*)d_in[6];
    float* out = (float*)d_out;

    unsigned short* patch_t = (unsigned short*)d_ws;           // 118784 B
    u32x4*          wfrag   = (u32x4*)((char*)d_ws + 118784);  // +20480 B

    void* args[] = {
        (void*)&mixer_x, (void*)&features, (void*)&W1, (void*)&b1,
        (void*)&W2, (void*)&b2, (void*)&node_patch,
        (void*)&patch_t, (void*)&wfrag, (void*)&out
    };
    hipLaunchCooperativeKernel((const void*)fused_mlp, dim3(256),
                               dim3(K2_THREADS), args, 0, stream);
}

// Round 21
// 25.499 us; speedup vs baseline: 3.2948x; 3.2948x over previous
//
#include <hip/hip_runtime.h>
#include <hip/hip_bf16.h>

#define N_NODES   200000
#define N_PATCHES 256
#define TSTEPS    12
#define NHID      16
#define HORIZON   12
#define GDIM      192            // NHID * TSTEPS
#define IN_DIM    204            // GDIM + TSTEPS
#define NPAIRS    3125           // N_NODES / 64 (exact)
#define K2_THREADS 512
#define TOTAL_WAVES 2048         // 256 blocks x 8 waves

// Tiled PH layout: row = patch p, 464 B (29 uint4). Slot (t, hi, G) = 8 B
// (4 bf16) holding cols t*32 + 8G + 4hi + {0..3}; offset (t*8+hi*4+G)*8 B.
#define TROW_U16  232            // u16 per row (464 B)
#define TROW_U4   29             // uint4 per row
#define TBL_U4    7424           // 256 * 29

typedef __attribute__((ext_vector_type(8)))  short        bf16x8;
typedef __attribute__((ext_vector_type(16))) float        f32x16;
typedef __attribute__((ext_vector_type(4)))  unsigned int u32x4;

// cold-path pack (K1 only): software RNE
__device__ __forceinline__ unsigned int pk2(float lo, float hi) {
    unsigned short l = __builtin_bit_cast(unsigned short, __float2bfloat16(lo));
    unsigned short h = __builtin_bit_cast(unsigned short, __float2bfloat16(hi));
    return ((unsigned int)h << 16) | (unsigned int)l;
}

// hot-path pack: single HW instruction (RNE, bit-identical to pk2)
__device__ __forceinline__ unsigned int cvtpk(float lo, float hi) {
    unsigned int r;
    asm("v_cvt_pk_bf16_f32 %0, %1, %2" : "=v"(r) : "v"(lo), "v"(hi));
    return r;
}

__device__ __forceinline__ bf16x8 frag_of(unsigned int a, unsigned int b,
                                          unsigned int c, unsigned int d) {
    u32x4 u; u[0] = a; u[1] = b; u[2] = c; u[3] = d;
    return __builtin_bit_cast(bf16x8, u);
}

__device__ __forceinline__ float bf16bits_lo(unsigned int w) {
    return __builtin_bit_cast(float, w << 16);
}
__device__ __forceinline__ float bf16bits_hi(unsigned int w) {
    return __builtin_bit_cast(float, w & 0xffff0000u);
}

// async global->LDS copy, 16B per lane (wave-uniform base + lane*16 dest)
__device__ __forceinline__ void gload_lds16(const uint4* g, uint4* l) {
    __builtin_amdgcn_global_load_lds(
        (const __attribute__((address_space(1))) unsigned int*)g,
        (__attribute__((address_space(3))) unsigned int*)l,
        16, 0, 0);
}

// Clamped weight fetch helpers (OOB -> 0)
__device__ __forceinline__ float ldW1f(const float* __restrict__ W1, int k, int j) {
    const bool ok = (k < TSTEPS) && (j < IN_DIM);
    const int  idx = ok ? ((GDIM + k) * IN_DIM + j) : 0;
    const float v = W1[idx];
    return ok ? v : 0.0f;
}
__device__ __forceinline__ float ldW2t(const float* __restrict__ W2, int j, int o) {
    const bool ok = (j < IN_DIM) && (o < HORIZON);
    const int  idx = ok ? (j * HORIZON + o) : 0;
    const float v = W2[idx];
    return ok ? v : 0.0f;
}

// col j -> u16 index within a tiled row
__device__ __forceinline__ int tiled_idx(int j) {
    const int t = j >> 5, w = j & 31;
    const int G = w >> 3, hb = (w >> 2) & 1, q = w & 3;
    return ((t * 8 + hb * 4 + G) << 2) + q;
}

// expand one uint4 (8 bf16) into acc elements [e0..e0+7]
__device__ __forceinline__ void expand8(const uint4& r, f32x16& acc, int e0) {
    acc[e0 + 0] = bf16bits_lo(r.x); acc[e0 + 1] = bf16bits_hi(r.x);
    acc[e0 + 2] = bf16bits_lo(r.y); acc[e0 + 3] = bf16bits_hi(r.y);
    acc[e0 + 4] = bf16bits_lo(r.z); acc[e0 + 5] = bf16bits_hi(r.z);
    acc[e0 + 6] = bf16bits_lo(r.w); acc[e0 + 7] = bf16bits_hi(r.w);
}

// ---------------------------------------------------------------------------
// Kernel 1 (grid 257 x 1024) — EXACT R16 version (proven).
// ---------------------------------------------------------------------------
__global__ __launch_bounds__(1024) void precompute(
    const float* __restrict__ mixer_x,   // (1,12,256,16)
    const float* __restrict__ W1,        // (204,204)
    const float* __restrict__ b1,        // (204)
    const float* __restrict__ W2,        // (204,12)
    unsigned short* __restrict__ patch_t, // (256,232) bf16 tiled
    u32x4* __restrict__ wfrag)           // (20,64)
{
    const int blk = blockIdx.x;
    const int tid = threadIdx.x;

    if (blk == N_PATCHES) {
        const int lane = tid & 63;
        const int g    = tid >> 6;        // 0..15
        const int jl   = lane & 31;
        const int kb   = 4 * (lane >> 5);
        for (int f = g; f < 20; f += 16) {
            u32x4 u;
            if (f < 7) {
                const int j = f * 32 + jl;
                u[0] = pk2(ldW1f(W1, kb + 0,  j), ldW1f(W1, kb + 1,  j));
                u[1] = pk2(ldW1f(W1, kb + 2,  j), ldW1f(W1, kb + 3,  j));
                u[2] = pk2(ldW1f(W1, kb + 8,  j), ldW1f(W1, kb + 9,  j));
                u[3] = pk2(ldW1f(W1, kb + 10, j), ldW1f(W1, kb + 11, j));
            } else {
                const int j0 = (f - 7) * 16 + kb;
                u[0] = pk2(ldW2t(W2, j0 + 0,  jl), ldW2t(W2, j0 + 1,  jl));
                u[1] = pk2(ldW2t(W2, j0 + 2,  jl), ldW2t(W2, j0 + 3,  jl));
                u[2] = pk2(ldW2t(W2, j0 + 8,  jl), ldW2t(W2, j0 + 9,  jl));
                u[3] = pk2(ldW2t(W2, j0 + 10, jl), ldW2t(W2, j0 + 11, jl));
            }
            wfrag[f * 64 + lane] = u;
        }
        return;
    }

    __shared__ float xs[GDIM];
    __shared__ float partial[3 * IN_DIM];
    const int p = blk;
    const int j = tid & 255;
    const int q = tid >> 8;               // i-quarter 0..3

    if (tid < GDIM) {
        const int t = tid >> 4, f = tid & 15;
        xs[tid] = mixer_x[(t * N_PATCHES + p) * NHID + f];
    }
    __syncthreads();

    float acc = 0.0f;
    if (j < IN_DIM) {
        acc = (q == 0) ? b1[j] : 0.0f;
        const int ibase = q * 48;
#pragma unroll 16
        for (int i = 0; i < 48; ++i)
            acc = fmaf(xs[ibase + i], W1[(ibase + i) * IN_DIM + j], acc);
        if (q > 0) partial[(q - 1) * IN_DIM + j] = acc;
    }
    __syncthreads();
    if (q == 0) {
        if (j < IN_DIM) {
            const float v = acc + partial[j] + partial[IN_DIM + j] + partial[2 * IN_DIM + j];
            patch_t[p * TROW_U16 + tiled_idx(j)] =
                __builtin_bit_cast(unsigned short, __float2bfloat16(v));
        } else if (j < 224) {
            patch_t[p * TROW_U16 + tiled_idx(j)] = 0;   // zero pad cols 204..223
        }
    }
}

// ---------------------------------------------------------------------------
// Kernel 2 (grid 256 x 512, 118784 B LDS) — R18 math; SINGLE CHANGE:
// PAIR-ILP chunk loop. Each wave owns a pair of adjacent 32-node chunks
// (pair pr -> nodes 64pr..64pr+63; 3125 pairs exact; stride 2048). Two
// independent ds_read->expand->MFMA->cvtpk->MFMA chains per wave double the
// chain-level parallelism in the now-latency-bound regime (post-cvtpk,
// all pipes <30%). Single accumulator per chain (holds VGPR in budget).
// ---------------------------------------------------------------------------
__global__ __launch_bounds__(K2_THREADS) void node_mlp_mfma(
    const float* __restrict__ features,       // (200000,12)
    const int*   __restrict__ node_patch,     // (200000)
    const unsigned short* __restrict__ patch_t, // (256,232) bf16 tiled
    const u32x4* __restrict__ wfrag,          // (20,64)
    const float* __restrict__ b2,             // (12)
    float* __restrict__ out)                  // (200000,12)
{
    __shared__ unsigned short smem[N_PATCHES * TROW_U16];   // 118784 B

    const int tid  = threadIdx.x;
    const int lane = tid & 63;
    const int wid  = tid >> 6;
    const int jl   = lane & 31;
    const int hi   = lane >> 5;
    const int hi2  = hi * 2;

    // ---- first pair's loads: issue before staging -------------------------
    int pr = blockIdx.x * 8 + wid;                        // 0..2047
    float4 faA, fbA, fcA, faB, fbB, fcB; int pA, pB;
    {
        const int nA = pr * 64 + jl;
        const float4* fpA = (const float4*)(features + nA * TSTEPS);
        const float4* fpB = (const float4*)(features + (nA + 32) * TSTEPS);
        faA = fpA[0]; fbA = fpA[1]; fcA = fpA[2];
        faB = fpB[0]; fbB = fpB[1]; fcB = fpB[2];
        pA  = node_patch[nA];
        pB  = node_patch[nA + 32];
    }

    bf16x8 A1f[7], A2f[13];
#pragma unroll
    for (int f = 0; f < 7; ++f)
        A1f[f] = __builtin_bit_cast(bf16x8, wfrag[f * 64 + lane]);
#pragma unroll
    for (int f = 0; f < 13; ++f)
        A2f[f] = __builtin_bit_cast(bf16x8, wfrag[(7 + f) * 64 + lane]);

    const float4 b2A = *(const float4*)(b2 + 4 * hi);     // b2[0..3] / b2[4..7]
    const float4 b2B = *(const float4*)(b2 + 8);          // b2[8..11] (hi0)

    // ---- async stage tiled bf16 patch table -> LDS ------------------------
    {
        const uint4* src = (const uint4*)patch_t;
        uint4* dst = (uint4*)smem;
#pragma unroll
        for (int k = 0; k < 15; ++k) {
            const int i = tid + k * K2_THREADS;
            if (i < TBL_U4) gload_lds16(src + i, dst + i);
        }
    }
    __syncthreads();   // drains vmcnt (incl. global_load_lds) + lgkm

    const uint4* ph4 = (const uint4*)smem;

    // ---- pair loop ---------------------------------------------------------
    while (true) {
        // B1 operands: F^T[k][node], stacked layout (k>=12 -> 0), HW pack
        const bf16x8 B1A = frag_of(hi ? cvtpk(fbA.x, fbA.y) : cvtpk(faA.x, faA.y),
                                   hi ? cvtpk(fbA.z, fbA.w) : cvtpk(faA.z, faA.w),
                                   hi ? 0u                  : cvtpk(fcA.x, fcA.y),
                                   hi ? 0u                  : cvtpk(fcA.z, fcA.w));
        const bf16x8 B1B = frag_of(hi ? cvtpk(fbB.x, fbB.y) : cvtpk(faB.x, faB.y),
                                   hi ? cvtpk(fbB.z, fbB.w) : cvtpk(faB.z, faB.w),
                                   hi ? 0u                  : cvtpk(fcB.x, fcB.y),
                                   hi ? 0u                  : cvtpk(fcB.z, fcB.w));

        const int pbA = pA * TROW_U4 + hi2;
        const int pbB = pB * TROW_U4 + hi2;

        f32x16 oA, oB;
#pragma unroll
        for (int e = 0; e < 16; ++e) { oA[e] = 0.0f; oB[e] = 0.0f; }

#pragma unroll
        for (int t = 0; t < 7; ++t) {
            // 4 independent b128 reads (2 per chain)
            const uint4 raA = ph4[pbA + t * 4];
            const uint4 rbA = ph4[pbA + t * 4 + 1];
            const uint4 raB = ph4[pbB + t * 4];
            const uint4 rbB = ph4[pbB + t * 4 + 1];

            f32x16 accA, accB;
            expand8(raA, accA, 0); expand8(rbA, accA, 8);
            expand8(raB, accB, 0); expand8(rbB, accB, 8);

            accA = __builtin_amdgcn_mfma_f32_32x32x16_bf16(A1f[t], B1A, accA, 0, 0, 0);
            accB = __builtin_amdgcn_mfma_f32_32x32x16_bf16(A1f[t], B1B, accB, 0, 0, 0);

            const bf16x8 baA = frag_of(
                cvtpk(fmaxf(accA[0], 0.f), fmaxf(accA[1], 0.f)),
                cvtpk(fmaxf(accA[2], 0.f), fmaxf(accA[3], 0.f)),
                cvtpk(fmaxf(accA[4], 0.f), fmaxf(accA[5], 0.f)),
                cvtpk(fmaxf(accA[6], 0.f), fmaxf(accA[7], 0.f)));
            const bf16x8 baB = frag_of(
                cvtpk(fmaxf(accB[0], 0.f), fmaxf(accB[1], 0.f)),
                cvtpk(fmaxf(accB[2], 0.f), fmaxf(accB[3], 0.f)),
                cvtpk(fmaxf(accB[4], 0.f), fmaxf(accB[5], 0.f)),
                cvtpk(fmaxf(accB[6], 0.f), fmaxf(accB[7], 0.f)));
            oA = __builtin_amdgcn_mfma_f32_32x32x16_bf16(A2f[2 * t], baA, oA, 0, 0, 0);
            oB = __builtin_amdgcn_mfma_f32_32x32x16_bf16(A2f[2 * t], baB, oB, 0, 0, 0);

            if (t < 6) {
                const bf16x8 bbA = frag_of(
                    cvtpk(fmaxf(accA[8],  0.f), fmaxf(accA[9],  0.f)),
                    cvtpk(fmaxf(accA[10], 0.f), fmaxf(accA[11], 0.f)),
                    cvtpk(fmaxf(accA[12], 0.f), fmaxf(accA[13], 0.f)),
                    cvtpk(fmaxf(accA[14], 0.f), fmaxf(accA[15], 0.f)));
                const bf16x8 bbB = frag_of(
                    cvtpk(fmaxf(accB[8],  0.f), fmaxf(accB[9],  0.f)),
                    cvtpk(fmaxf(accB[10], 0.f), fmaxf(accB[11], 0.f)),
                    cvtpk(fmaxf(accB[12], 0.f), fmaxf(accB[13], 0.f)),
                    cvtpk(fmaxf(accB[14], 0.f), fmaxf(accB[15], 0.f)));
                oA = __builtin_amdgcn_mfma_f32_32x32x16_bf16(A2f[2 * t + 1], bbA, oA, 0, 0, 0);
                oB = __builtin_amdgcn_mfma_f32_32x32x16_bf16(A2f[2 * t + 1], bbB, oB, 0, 0, 0);
            }
        }

        // ---- stores: D row of elem e = (e&3)+8*(e>>2)+4*hi, col = node ----
        {
            const int nA = pr * 64 + jl;
            float* orow = out + nA * HORIZON;
            if (hi == 0) {
                *(float4*)(orow + 0) = make_float4(oA[0] + b2A.x, oA[1] + b2A.y,
                                                   oA[2] + b2A.z, oA[3] + b2A.w);
                *(float4*)(orow + 8) = make_float4(oA[4] + b2B.x, oA[5] + b2B.y,
                                                   oA[6] + b2B.z, oA[7] + b2B.w);
            } else {
                *(float4*)(orow + 4) = make_float4(oA[0] + b2A.x, oA[1] + b2A.y,
                                                   oA[2] + b2A.z, oA[3] + b2A.w);
            }
        }
        {
            const int nB = pr * 64 + 32 + jl;
            float* orow = out + nB * HORIZON;
            if (hi == 0) {
                *(float4*)(orow + 0) = make_float4(oB[0] + b2A.x, oB[1] + b2A.y,
                                                   oB[2] + b2A.z, oB[3] + b2A.w);
                *(float4*)(orow + 8) = make_float4(oB[4] + b2B.x, oB[5] + b2B.y,
                                                   oB[6] + b2B.z, oB[7] + b2B.w);
            } else {
                *(float4*)(orow + 4) = make_float4(oB[0] + b2A.x, oB[1] + b2A.y,
                                                   oB[2] + b2A.z, oB[3] + b2A.w);
            }
        }

        pr += TOTAL_WAVES;
        if (pr >= NPAIRS) break;

        // next pair's loads
        const int nA = pr * 64 + jl;
        const float4* fpA = (const float4*)(features + nA * TSTEPS);
        const float4* fpB = (const float4*)(features + (nA + 32) * TSTEPS);
        faA = fpA[0]; fbA = fpA[1]; fcA = fpA[2];
        faB = fpB[0]; fbB = fpB[1]; fcB = fpB[2];
        pA  = node_patch[nA];
        pB  = node_patch[nA + 32];
    }
}

// ---------------------------------------------------------------------------
extern "C" void kernel_launch(void* const* d_in, const int* in_sizes, int n_in,
                              void* d_out, int out_size, void* d_ws, size_t ws_size,
                              hipStream_t stream) {
    const float* mixer_x    = (const float*)d_in[0];
    const float* features   = (const float*)d_in[1];
    const float* W1         = (const float*)d_in[2];
    const float* b1         = (const float*)d_in[3];
    const float* W2         = (const float*)d_in[4];
    const float* b2         = (const float*)d_in[5];
    const int*   node_patch = (const int*)d_in[6];
    float* out = (float*)d_out;

    unsigned short* patch_t = (unsigned short*)d_ws;           // 118784 B
    u32x4*          wfrag   = (u32x4*)((char*)d_ws + 118784);  // +20480 B

    precompute<<<257, 1024, 0, stream>>>(mixer_x, W1, b1, W2, patch_t, wfrag);

    node_mlp_mfma<<<256, K2_THREADS, 0, stream>>>(features, node_patch,
                                                  patch_t, wfrag, b2, out);
}

// Round 22
// 23.393 us; speedup vs baseline: 3.5915x; 1.0900x over previous
//
#include <hip/hip_runtime.h>
#include <hip/hip_bf16.h>

#define N_NODES   200000
#define N_PATCHES 256
#define TSTEPS    12
#define NHID      16
#define HORIZON   12
#define GDIM      192            // NHID * TSTEPS
#define IN_DIM    204            // GDIM + TSTEPS
#define NCHUNKS   6250           // N_NODES / 32 (exact)
#define K2_THREADS 512
#define TOTAL_WAVES 2048         // 256 blocks x 8 waves

// Tiled PH layout: row = patch p, 464 B (29 uint4). Slot (t, hi, G) = 8 B
// (4 bf16) holding cols t*32 + 8G + 4hi + {0..3}; offset (t*8+hi*4+G)*8 B.
#define TROW_U16  232            // u16 per row (464 B)
#define TROW_U4   29             // uint4 per row
#define TBL_U4    7424           // 256 * 29

typedef __attribute__((ext_vector_type(8)))  short        bf16x8;
typedef __attribute__((ext_vector_type(16))) float        f32x16;
typedef __attribute__((ext_vector_type(4)))  unsigned int u32x4;

// cold-path pack (K1 only): software RNE
__device__ __forceinline__ unsigned int pk2(float lo, float hi) {
    unsigned short l = __builtin_bit_cast(unsigned short, __float2bfloat16(lo));
    unsigned short h = __builtin_bit_cast(unsigned short, __float2bfloat16(hi));
    return ((unsigned int)h << 16) | (unsigned int)l;
}

// hot-path pack: single HW instruction (RNE, bit-identical to pk2):
// dst = { bf16(hi) << 16 | bf16(lo) }
__device__ __forceinline__ unsigned int cvtpk(float lo, float hi) {
    unsigned int r;
    asm("v_cvt_pk_bf16_f32 %0, %1, %2" : "=v"(r) : "v"(lo), "v"(hi));
    return r;
}

__device__ __forceinline__ bf16x8 frag_of(unsigned int a, unsigned int b,
                                          unsigned int c, unsigned int d) {
    u32x4 u; u[0] = a; u[1] = b; u[2] = c; u[3] = d;
    return __builtin_bit_cast(bf16x8, u);
}

__device__ __forceinline__ float bf16bits_lo(unsigned int w) {
    return __builtin_bit_cast(float, w << 16);
}
__device__ __forceinline__ float bf16bits_hi(unsigned int w) {
    return __builtin_bit_cast(float, w & 0xffff0000u);
}

// async global->LDS copy, 16B per lane (wave-uniform base + lane*16 dest)
__device__ __forceinline__ void gload_lds16(const uint4* g, uint4* l) {
    __builtin_amdgcn_global_load_lds(
        (const __attribute__((address_space(1))) unsigned int*)g,
        (__attribute__((address_space(3))) unsigned int*)l,
        16, 0, 0);
}

// Clamped weight fetch helpers (OOB -> 0)
__device__ __forceinline__ float ldW1f(const float* __restrict__ W1, int k, int j) {
    const bool ok = (k < TSTEPS) && (j < IN_DIM);
    const int  idx = ok ? ((GDIM + k) * IN_DIM + j) : 0;
    const float v = W1[idx];
    return ok ? v : 0.0f;
}
__device__ __forceinline__ float ldW2t(const float* __restrict__ W2, int j, int o) {
    const bool ok = (j < IN_DIM) && (o < HORIZON);
    const int  idx = ok ? (j * HORIZON + o) : 0;
    const float v = W2[idx];
    return ok ? v : 0.0f;
}

// col j -> u16 index within a tiled row
__device__ __forceinline__ int tiled_idx(int j) {
    const int t = j >> 5, w = j & 31;
    const int G = w >> 3, hb = (w >> 2) & 1, q = w & 3;
    return ((t * 8 + hb * 4 + G) << 2) + q;
}

// ---------------------------------------------------------------------------
// Kernel 1 (grid 257 x 1024):
//  blocks 0..255 : PH[p][j] = b1[j] + sum_{i<192} x[p][i]*W1[i][j], stored
//                  tiled bf16 at patch_t[p*232 + tiled_idx(j)]; pads zeroed.
//  block 256     : pack per-lane MFMA weight fragments (stacked k-layout
//                  m(e,hi) = (e&3)+8*(e>>2)+4*hi) into wfrag.
// ---------------------------------------------------------------------------
__global__ __launch_bounds__(1024) void precompute(
    const float* __restrict__ mixer_x,   // (1,12,256,16)
    const float* __restrict__ W1,        // (204,204)
    const float* __restrict__ b1,        // (204)
    const float* __restrict__ W2,        // (204,12)
    unsigned short* __restrict__ patch_t, // (256,232) bf16 tiled
    u32x4* __restrict__ wfrag)           // (20,64)
{
    const int blk = blockIdx.x;
    const int tid = threadIdx.x;

    if (blk == N_PATCHES) {
        const int lane = tid & 63;
        const int g    = tid >> 6;        // 0..15
        const int jl   = lane & 31;
        const int kb   = 4 * (lane >> 5);
        for (int f = g; f < 20; f += 16) {
            u32x4 u;
            if (f < 7) {
                const int j = f * 32 + jl;
                u[0] = pk2(ldW1f(W1, kb + 0,  j), ldW1f(W1, kb + 1,  j));
                u[1] = pk2(ldW1f(W1, kb + 2,  j), ldW1f(W1, kb + 3,  j));
                u[2] = pk2(ldW1f(W1, kb + 8,  j), ldW1f(W1, kb + 9,  j));
                u[3] = pk2(ldW1f(W1, kb + 10, j), ldW1f(W1, kb + 11, j));
            } else {
                const int j0 = (f - 7) * 16 + kb;
                u[0] = pk2(ldW2t(W2, j0 + 0,  jl), ldW2t(W2, j0 + 1,  jl));
                u[1] = pk2(ldW2t(W2, j0 + 2,  jl), ldW2t(W2, j0 + 3,  jl));
                u[2] = pk2(ldW2t(W2, j0 + 8,  jl), ldW2t(W2, j0 + 9,  jl));
                u[3] = pk2(ldW2t(W2, j0 + 10, jl), ldW2t(W2, j0 + 11, jl));
            }
            wfrag[f * 64 + lane] = u;
        }
        return;
    }

    __shared__ float xs[GDIM];
    __shared__ float partial[3 * IN_DIM];
    const int p = blk;
    const int j = tid & 255;
    const int q = tid >> 8;               // i-quarter 0..3

    if (tid < GDIM) {
        const int t = tid >> 4, f = tid & 15;
        xs[tid] = mixer_x[(t * N_PATCHES + p) * NHID + f];
    }
    __syncthreads();

    float acc = 0.0f;
    if (j < IN_DIM) {
        acc = (q == 0) ? b1[j] : 0.0f;
        const int ibase = q * 48;
#pragma unroll 16
        for (int i = 0; i < 48; ++i)
            acc = fmaf(xs[ibase + i], W1[(ibase + i) * IN_DIM + j], acc);
        if (q > 0) partial[(q - 1) * IN_DIM + j] = acc;
    }
    __syncthreads();
    if (q == 0) {
        if (j < IN_DIM) {
            const float v = acc + partial[j] + partial[IN_DIM + j] + partial[2 * IN_DIM + j];
            patch_t[p * TROW_U16 + tiled_idx(j)] =
                __builtin_bit_cast(unsigned short, __float2bfloat16(v));
        } else if (j < 224) {
            patch_t[p * TROW_U16 + tiled_idx(j)] = 0;   // zero pad cols 204..223
        }
    }
}

// ---------------------------------------------------------------------------
// Kernel 2 (grid 256 x 512, 118784 B LDS) — session-best (R18, 23.4 us):
// async-stage tiled bf16 patch table to LDS, then per-wave MFMA over chunks
// of 32 consecutive nodes (c = blk*8+wid, stride 2048). C-init = 2x
// ds_read_b128 per tile (ping-pong prefetched), hot packs via
// v_cvt_pk_bf16_f32, GEMM2 even/odd accumulators.
// ---------------------------------------------------------------------------
__global__ __launch_bounds__(K2_THREADS) void node_mlp_mfma(
    const float* __restrict__ features,       // (200000,12)
    const int*   __restrict__ node_patch,     // (200000)
    const unsigned short* __restrict__ patch_t, // (256,232) bf16 tiled
    const u32x4* __restrict__ wfrag,          // (20,64)
    const float* __restrict__ b2,             // (12)
    float* __restrict__ out)                  // (200000,12)
{
    __shared__ unsigned short smem[N_PATCHES * TROW_U16];   // 118784 B

    const int tid  = threadIdx.x;
    const int lane = tid & 63;
    const int wid  = tid >> 6;
    const int jl   = lane & 31;
    const int hi   = lane >> 5;
    const int hi2  = hi * 2;

    // ---- first chunk's loads: issue before staging ------------------------
    int c = blockIdx.x * 8 + wid;                         // 0..2047
    float4 fa, fb, fc; int p;
    {
        const float4* fp = (const float4*)(features + (c * 32 + jl) * TSTEPS);
        fa = fp[0]; fb = fp[1]; fc = fp[2];
        p  = node_patch[c * 32 + jl];
    }

    bf16x8 A1f[7], A2f[13];
#pragma unroll
    for (int f = 0; f < 7; ++f)
        A1f[f] = __builtin_bit_cast(bf16x8, wfrag[f * 64 + lane]);
#pragma unroll
    for (int f = 0; f < 13; ++f)
        A2f[f] = __builtin_bit_cast(bf16x8, wfrag[(7 + f) * 64 + lane]);

    const float4 b2A = *(const float4*)(b2 + 4 * hi);     // b2[0..3] / b2[4..7]
    const float4 b2B = *(const float4*)(b2 + 8);          // b2[8..11] (hi0)

    // ---- async stage tiled bf16 patch table -> LDS ------------------------
    {
        const uint4* src = (const uint4*)patch_t;
        uint4* dst = (uint4*)smem;
#pragma unroll
        for (int k = 0; k < 15; ++k) {
            const int i = tid + k * K2_THREADS;
            if (i < TBL_U4) gload_lds16(src + i, dst + i);
        }
    }
    __syncthreads();   // drains vmcnt (incl. global_load_lds) + lgkm

    const uint4* ph4 = (const uint4*)smem;

    // ---- chunk loop --------------------------------------------------------
    while (true) {
        const int  cn    = c + TOTAL_WAVES;
        const bool haveN = (cn < NCHUNKS);
        float4 fa2, fb2, fc2; int p2 = 0;
        if (haveN) {                                      // prefetch next chunk
            const float4* fq = (const float4*)(features + (cn * 32 + jl) * TSTEPS);
            fa2 = fq[0]; fb2 = fq[1]; fc2 = fq[2];
            p2  = node_patch[cn * 32 + jl];
        }

        // B1: F^T[k][node], stacked layout (k>=12 -> 0), HW pack
        const bf16x8 B1 = frag_of(hi ? cvtpk(fb.x, fb.y) : cvtpk(fa.x, fa.y),
                                  hi ? cvtpk(fb.z, fb.w) : cvtpk(fa.z, fa.w),
                                  hi ? 0u                : cvtpk(fc.x, fc.y),
                                  hi ? 0u                : cvtpk(fc.z, fc.w));

        const int pbase = p * TROW_U4 + hi2;

        f32x16 oE, oO;
#pragma unroll
        for (int e = 0; e < 16; ++e) { oE[e] = 0.0f; oO[e] = 0.0f; }

        // ping-pong C-init prefetch (2 x b128 per tile)
        uint4 nxa[2], nxb[2];
        nxa[0] = ph4[pbase];
        nxb[0] = ph4[pbase + 1];

#pragma unroll
        for (int t = 0; t < 7; ++t) {
            const uint4 ra = nxa[t & 1];
            const uint4 rb = nxb[t & 1];
            if (t < 6) {                                  // prefetch tile t+1
                nxa[(t + 1) & 1] = ph4[pbase + (t + 1) * 4];
                nxb[(t + 1) & 1] = ph4[pbase + (t + 1) * 4 + 1];
            }

            f32x16 acc;
            acc[0]  = bf16bits_lo(ra.x); acc[1]  = bf16bits_hi(ra.x);
            acc[2]  = bf16bits_lo(ra.y); acc[3]  = bf16bits_hi(ra.y);
            acc[4]  = bf16bits_lo(ra.z); acc[5]  = bf16bits_hi(ra.z);
            acc[6]  = bf16bits_lo(ra.w); acc[7]  = bf16bits_hi(ra.w);
            acc[8]  = bf16bits_lo(rb.x); acc[9]  = bf16bits_hi(rb.x);
            acc[10] = bf16bits_lo(rb.y); acc[11] = bf16bits_hi(rb.y);
            acc[12] = bf16bits_lo(rb.z); acc[13] = bf16bits_hi(rb.z);
            acc[14] = bf16bits_lo(rb.w); acc[15] = bf16bits_hi(rb.w);

            acc = __builtin_amdgcn_mfma_f32_32x32x16_bf16(A1f[t], B1, acc, 0, 0, 0);

            // relu + HW pack: acc element order IS the B-operand element order
            const bf16x8 ba = frag_of(
                cvtpk(fmaxf(acc[0], 0.f), fmaxf(acc[1], 0.f)),
                cvtpk(fmaxf(acc[2], 0.f), fmaxf(acc[3], 0.f)),
                cvtpk(fmaxf(acc[4], 0.f), fmaxf(acc[5], 0.f)),
                cvtpk(fmaxf(acc[6], 0.f), fmaxf(acc[7], 0.f)));
            oE = __builtin_amdgcn_mfma_f32_32x32x16_bf16(A2f[2 * t], ba, oE, 0, 0, 0);

            if (t < 6) {
                const bf16x8 bb = frag_of(
                    cvtpk(fmaxf(acc[8],  0.f), fmaxf(acc[9],  0.f)),
                    cvtpk(fmaxf(acc[10], 0.f), fmaxf(acc[11], 0.f)),
                    cvtpk(fmaxf(acc[12], 0.f), fmaxf(acc[13], 0.f)),
                    cvtpk(fmaxf(acc[14], 0.f), fmaxf(acc[15], 0.f)));
                oO = __builtin_amdgcn_mfma_f32_32x32x16_bf16(A2f[2 * t + 1], bb, oO, 0, 0, 0);
            }
        }

        // ---- store: D row of elem e = (e&3)+8*(e>>2)+4*hi, col = node -----
        {
            const int node = c * 32 + jl;                 // always < N_NODES
            float* orow = out + node * HORIZON;
            const float s0 = oE[0] + oO[0], s1 = oE[1] + oO[1];
            const float s2 = oE[2] + oO[2], s3 = oE[3] + oO[3];
            if (hi == 0) {
                const float s4 = oE[4] + oO[4], s5 = oE[5] + oO[5];
                const float s6 = oE[6] + oO[6], s7 = oE[7] + oO[7];
                *(float4*)(orow + 0) = make_float4(s0 + b2A.x, s1 + b2A.y,
                                                   s2 + b2A.z, s3 + b2A.w);
                *(float4*)(orow + 8) = make_float4(s4 + b2B.x, s5 + b2B.y,
                                                   s6 + b2B.z, s7 + b2B.w);
            } else {
                *(float4*)(orow + 4) = make_float4(s0 + b2A.x, s1 + b2A.y,
                                                   s2 + b2A.z, s3 + b2A.w);
            }
        }

        if (!haveN) break;
        fa = fa2; fb = fb2; fc = fc2; p = p2; c = cn;
    }
}

// ---------------------------------------------------------------------------
extern "C" void kernel_launch(void* const* d_in, const int* in_sizes, int n_in,
                              void* d_out, int out_size, void* d_ws, size_t ws_size,
                              hipStream_t stream) {
    const float* mixer_x    = (const float*)d_in[0];
    const float* features   = (const float*)d_in[1];
    const float* W1         = (const float*)d_in[2];
    const float* b1         = (const float*)d_in[3];
    const float* W2         = (const float*)d_in[4];
    const float* b2         = (const float*)d_in[5];
    const int*   node_patch = (const int*)d_in[6];
    float* out = (float*)d_out;

    unsigned short* patch_t = (unsigned short*)d_ws;           // 118784 B
    u32x4*          wfrag   = (u32x4*)((char*)d_ws + 118784);  // +20480 B

    precompute<<<257, 1024, 0, stream>>>(mixer_x, W1, b1, W2, patch_t, wfrag);

    node_mlp_mfma<<<256, K2_THREADS, 0, stream>>>(features, node_patch,
                                                  patch_t, wfrag, b2, out);
}

// Round 23
// 23.231 us; speedup vs baseline: 3.6165x; 1.0070x over previous
//
#include <hip/hip_runtime.h>
#include <hip/hip_bf16.h>

#define N_NODES   200000
#define N_PATCHES 256
#define TSTEPS    12
#define NHID      16
#define HORIZON   12
#define GDIM      192            // NHID * TSTEPS
#define IN_DIM    204            // GDIM + TSTEPS
#define NCHUNKS   6250           // N_NODES / 32 (exact)
#define K2_THREADS 512
#define TOTAL_WAVES 2048         // 256 blocks x 8 waves

// Tiled PH layout: row = patch p, 464 B (29 uint4). Slot (t, hi, G) = 8 B
// (4 bf16) holding cols t*32 + 8G + 4hi + {0..3}; offset (t*8+hi*4+G)*8 B.
// A b128 at slot pair (t,hi,{0,1}) therefore holds PH at col offsets
// m(e,hi) = (e&3)+8*(e>>2)+4*hi for e=0..7 — i.e. EXACT B-operand element
// order. K1 zeroes pad cols 204..223, so tile t=6 is in-row and zero-padded
// (this is what R13's stride-212 layout violated -> its 0.4 absmax).
#define TROW_U16  232            // u16 per row (464 B)
#define TROW_U4   29             // uint4 per row
#define TBL_U4    7424           // 256 * 29

typedef __attribute__((ext_vector_type(8)))  short        bf16x8;
typedef __attribute__((ext_vector_type(16))) float        f32x16;
typedef __attribute__((ext_vector_type(4)))  unsigned int u32x4;

// cold-path pack (K1 only): software RNE
__device__ __forceinline__ unsigned int pk2(float lo, float hi) {
    unsigned short l = __builtin_bit_cast(unsigned short, __float2bfloat16(lo));
    unsigned short h = __builtin_bit_cast(unsigned short, __float2bfloat16(hi));
    return ((unsigned int)h << 16) | (unsigned int)l;
}

// hot-path pack: single HW instruction (RNE, bit-identical to pk2)
__device__ __forceinline__ unsigned int cvtpk(float lo, float hi) {
    unsigned int r;
    asm("v_cvt_pk_bf16_f32 %0, %1, %2" : "=v"(r) : "v"(lo), "v"(hi));
    return r;
}

__device__ __forceinline__ bf16x8 frag_of(unsigned int a, unsigned int b,
                                          unsigned int c, unsigned int d) {
    u32x4 u; u[0] = a; u[1] = b; u[2] = c; u[3] = d;
    return __builtin_bit_cast(bf16x8, u);
}

// async global->LDS copy, 16B per lane (wave-uniform base + lane*16 dest)
__device__ __forceinline__ void gload_lds16(const uint4* g, uint4* l) {
    __builtin_amdgcn_global_load_lds(
        (const __attribute__((address_space(1))) unsigned int*)g,
        (__attribute__((address_space(3))) unsigned int*)l,
        16, 0, 0);
}

// Clamped weight fetch helpers (OOB -> 0)
__device__ __forceinline__ float ldW1f(const float* __restrict__ W1, int k, int j) {
    const bool ok = (k < TSTEPS) && (j < IN_DIM);
    const int  idx = ok ? ((GDIM + k) * IN_DIM + j) : 0;
    const float v = W1[idx];
    return ok ? v : 0.0f;
}
__device__ __forceinline__ float ldW2t(const float* __restrict__ W2, int j, int o) {
    const bool ok = (j < IN_DIM) && (o < HORIZON);
    const int  idx = ok ? (j * HORIZON + o) : 0;
    const float v = W2[idx];
    return ok ? v : 0.0f;
}

// col j -> u16 index within a tiled row
__device__ __forceinline__ int tiled_idx(int j) {
    const int t = j >> 5, w = j & 31;
    const int G = w >> 3, hb = (w >> 2) & 1, q = w & 3;
    return ((t * 8 + hb * 4 + G) << 2) + q;
}

// ---------------------------------------------------------------------------
// Kernel 1 (grid 257 x 1024) — EXACT R16/R18 version (proven).
// ---------------------------------------------------------------------------
__global__ __launch_bounds__(1024) void precompute(
    const float* __restrict__ mixer_x,   // (1,12,256,16)
    const float* __restrict__ W1,        // (204,204)
    const float* __restrict__ b1,        // (204)
    const float* __restrict__ W2,        // (204,12)
    unsigned short* __restrict__ patch_t, // (256,232) bf16 tiled
    u32x4* __restrict__ wfrag)           // (20,64)
{
    const int blk = blockIdx.x;
    const int tid = threadIdx.x;

    if (blk == N_PATCHES) {
        const int lane = tid & 63;
        const int g    = tid >> 6;        // 0..15
        const int jl   = lane & 31;
        const int kb   = 4 * (lane >> 5);
        for (int f = g; f < 20; f += 16) {
            u32x4 u;
            if (f < 7) {
                const int j = f * 32 + jl;
                u[0] = pk2(ldW1f(W1, kb + 0,  j), ldW1f(W1, kb + 1,  j));
                u[1] = pk2(ldW1f(W1, kb + 2,  j), ldW1f(W1, kb + 3,  j));
                u[2] = pk2(ldW1f(W1, kb + 8,  j), ldW1f(W1, kb + 9,  j));
                u[3] = pk2(ldW1f(W1, kb + 10, j), ldW1f(W1, kb + 11, j));
            } else {
                const int j0 = (f - 7) * 16 + kb;
                u[0] = pk2(ldW2t(W2, j0 + 0,  jl), ldW2t(W2, j0 + 1,  jl));
                u[1] = pk2(ldW2t(W2, j0 + 2,  jl), ldW2t(W2, j0 + 3,  jl));
                u[2] = pk2(ldW2t(W2, j0 + 8,  jl), ldW2t(W2, j0 + 9,  jl));
                u[3] = pk2(ldW2t(W2, j0 + 10, jl), ldW2t(W2, j0 + 11, jl));
            }
            wfrag[f * 64 + lane] = u;
        }
        return;
    }

    __shared__ float xs[GDIM];
    __shared__ float partial[3 * IN_DIM];
    const int p = blk;
    const int j = tid & 255;
    const int q = tid >> 8;               // i-quarter 0..3

    if (tid < GDIM) {
        const int t = tid >> 4, f = tid & 15;
        xs[tid] = mixer_x[(t * N_PATCHES + p) * NHID + f];
    }
    __syncthreads();

    float acc = 0.0f;
    if (j < IN_DIM) {
        acc = (q == 0) ? b1[j] : 0.0f;
        const int ibase = q * 48;
#pragma unroll 16
        for (int i = 0; i < 48; ++i)
            acc = fmaf(xs[ibase + i], W1[(ibase + i) * IN_DIM + j], acc);
        if (q > 0) partial[(q - 1) * IN_DIM + j] = acc;
    }
    __syncthreads();
    if (q == 0) {
        if (j < IN_DIM) {
            const float v = acc + partial[j] + partial[IN_DIM + j] + partial[2 * IN_DIM + j];
            patch_t[p * TROW_U16 + tiled_idx(j)] =
                __builtin_bit_cast(unsigned short, __float2bfloat16(v));
        } else if (j < 224) {
            patch_t[p * TROW_U16 + tiled_idx(j)] = 0;   // zero pad cols 204..223
        }
    }
}

// ---------------------------------------------------------------------------
// Kernel 2 (grid 256 x 512, 118784 B LDS) — R18 structure; SINGLE CHANGE:
// identity-MFMA C-init. The tiled b128 loads (ra, rb) are ALREADY in
// B-operand element order, so they bit_cast directly to fragments and the
// per-tile PH injection becomes
//   acc = mfma(A1f, B1, mfma(IAhi, rb, mfma(IAlo, ra, 0)))
// with one-hot IA fragments — deleting the 16-op/tile bf16->f32 VALU
// expansion (−112 VALU insts/chunk on the measured VALU-issue-bound path)
// for +2 MFMA/tile on the 15%-utilized MFMA pipe. Values exact (bf16 x 1.0
// accumulated in fp32).
// ---------------------------------------------------------------------------
__global__ __launch_bounds__(K2_THREADS) void node_mlp_mfma(
    const float* __restrict__ features,       // (200000,12)
    const int*   __restrict__ node_patch,     // (200000)
    const unsigned short* __restrict__ patch_t, // (256,232) bf16 tiled
    const u32x4* __restrict__ wfrag,          // (20,64)
    const float* __restrict__ b2,             // (12)
    float* __restrict__ out)                  // (200000,12)
{
    __shared__ unsigned short smem[N_PATCHES * TROW_U16];   // 118784 B

    const int tid  = threadIdx.x;
    const int lane = tid & 63;
    const int wid  = tid >> 6;
    const int jl   = lane & 31;
    const int hi   = lane >> 5;
    const int hi2  = hi * 2;

    // ---- first chunk's loads: issue before staging ------------------------
    int c = blockIdx.x * 8 + wid;                         // 0..2047
    float4 fa, fb, fc; int p;
    {
        const float4* fp = (const float4*)(features + (c * 32 + jl) * TSTEPS);
        fa = fp[0]; fb = fp[1]; fc = fp[2];
        p  = node_patch[c * 32 + jl];
    }

    bf16x8 A1f[7], A2f[13];
#pragma unroll
    for (int f = 0; f < 7; ++f)
        A1f[f] = __builtin_bit_cast(bf16x8, wfrag[f * 64 + lane]);
#pragma unroll
    for (int f = 0; f < 13; ++f)
        A2f[f] = __builtin_bit_cast(bf16x8, wfrag[(7 + f) * 64 + lane]);

    const float4 b2A = *(const float4*)(b2 + 4 * hi);     // b2[0..3] / b2[4..7]
    const float4 b2B = *(const float4*)(b2 + 8);          // b2[8..11] (hi0)

    // ---- identity A-fragments: one-hot rows (1.0bf16 = 0x3F80) ------------
    // IAlo: A[r][k] = d(r==k), r,k in 0..15 -> element e is 1 iff jl == m(e,hi)
    // IAhi: A[r][k] = d(r==16+k)            -> element e is 1 iff jl == 16+m
    bf16x8 IAlo, IAhi;
    {
        u32x4 lo, hi4;
#pragma unroll
        for (int g = 0; g < 4; ++g) {
            const int e0 = 2 * g, e1 = 2 * g + 1;
            const int m0 = (e0 & 3) + 8 * (e0 >> 2) + 4 * hi;
            const int m1 = (e1 & 3) + 8 * (e1 >> 2) + 4 * hi;
            const unsigned int a0 = (jl == m0)      ? 0x3F80u : 0u;
            const unsigned int a1 = (jl == m1)      ? 0x3F80u : 0u;
            const unsigned int c0 = (jl == 16 + m0) ? 0x3F80u : 0u;
            const unsigned int c1 = (jl == 16 + m1) ? 0x3F80u : 0u;
            lo[g]  = (a1 << 16) | a0;
            hi4[g] = (c1 << 16) | c0;
        }
        IAlo = __builtin_bit_cast(bf16x8, lo);
        IAhi = __builtin_bit_cast(bf16x8, hi4);
    }

    // ---- async stage tiled bf16 patch table -> LDS ------------------------
    {
        const uint4* src = (const uint4*)patch_t;
        uint4* dst = (uint4*)smem;
#pragma unroll
        for (int k = 0; k < 15; ++k) {
            const int i = tid + k * K2_THREADS;
            if (i < TBL_U4) gload_lds16(src + i, dst + i);
        }
    }
    __syncthreads();   // drains vmcnt (incl. global_load_lds) + lgkm

    const uint4* ph4 = (const uint4*)smem;

    f32x16 z16;
#pragma unroll
    for (int e = 0; e < 16; ++e) z16[e] = 0.0f;

    // ---- chunk loop --------------------------------------------------------
    while (true) {
        const int  cn    = c + TOTAL_WAVES;
        const bool haveN = (cn < NCHUNKS);
        float4 fa2, fb2, fc2; int p2 = 0;
        if (haveN) {                                      // prefetch next chunk
            const float4* fq = (const float4*)(features + (cn * 32 + jl) * TSTEPS);
            fa2 = fq[0]; fb2 = fq[1]; fc2 = fq[2];
            p2  = node_patch[cn * 32 + jl];
        }

        // B1: F^T[k][node], stacked layout (k>=12 -> 0), HW pack
        const bf16x8 B1 = frag_of(hi ? cvtpk(fb.x, fb.y) : cvtpk(fa.x, fa.y),
                                  hi ? cvtpk(fb.z, fb.w) : cvtpk(fa.z, fa.w),
                                  hi ? 0u                : cvtpk(fc.x, fc.y),
                                  hi ? 0u                : cvtpk(fc.z, fc.w));

        const int pbase = p * TROW_U4 + hi2;

        f32x16 oE, oO;
#pragma unroll
        for (int e = 0; e < 16; ++e) { oE[e] = 0.0f; oO[e] = 0.0f; }

        // ping-pong C-init prefetch (2 x b128 per tile)
        uint4 nxa[2], nxb[2];
        nxa[0] = ph4[pbase];
        nxb[0] = ph4[pbase + 1];

#pragma unroll
        for (int t = 0; t < 7; ++t) {
            const uint4 ra = nxa[t & 1];
            const uint4 rb = nxb[t & 1];
            if (t < 6) {                                  // prefetch tile t+1
                nxa[(t + 1) & 1] = ph4[pbase + (t + 1) * 4];
                nxb[(t + 1) & 1] = ph4[pbase + (t + 1) * 4 + 1];
            }

            // PH injection via identity MFMA (ra/rb are already B-order)
            const bf16x8 phLoF = __builtin_bit_cast(bf16x8, ra);
            const bf16x8 phHiF = __builtin_bit_cast(bf16x8, rb);
            f32x16 acc;
            acc = __builtin_amdgcn_mfma_f32_32x32x16_bf16(IAlo, phLoF, z16, 0, 0, 0);
            acc = __builtin_amdgcn_mfma_f32_32x32x16_bf16(IAhi, phHiF, acc, 0, 0, 0);
            acc = __builtin_amdgcn_mfma_f32_32x32x16_bf16(A1f[t], B1, acc, 0, 0, 0);

            // relu + HW pack: acc element order IS the B-operand element order
            const bf16x8 ba = frag_of(
                cvtpk(fmaxf(acc[0], 0.f), fmaxf(acc[1], 0.f)),
                cvtpk(fmaxf(acc[2], 0.f), fmaxf(acc[3], 0.f)),
                cvtpk(fmaxf(acc[4], 0.f), fmaxf(acc[5], 0.f)),
                cvtpk(fmaxf(acc[6], 0.f), fmaxf(acc[7], 0.f)));
            oE = __builtin_amdgcn_mfma_f32_32x32x16_bf16(A2f[2 * t], ba, oE, 0, 0, 0);

            if (t < 6) {
                const bf16x8 bb = frag_of(
                    cvtpk(fmaxf(acc[8],  0.f), fmaxf(acc[9],  0.f)),
                    cvtpk(fmaxf(acc[10], 0.f), fmaxf(acc[11], 0.f)),
                    cvtpk(fmaxf(acc[12], 0.f), fmaxf(acc[13], 0.f)),
                    cvtpk(fmaxf(acc[14], 0.f), fmaxf(acc[15], 0.f)));
                oO = __builtin_amdgcn_mfma_f32_32x32x16_bf16(A2f[2 * t + 1], bb, oO, 0, 0, 0);
            }
        }

        // ---- store: D row of elem e = (e&3)+8*(e>>2)+4*hi, col = node -----
        {
            const int node = c * 32 + jl;                 // always < N_NODES
            float* orow = out + node * HORIZON;
            const float s0 = oE[0] + oO[0], s1 = oE[1] + oO[1];
            const float s2 = oE[2] + oO[2], s3 = oE[3] + oO[3];
            if (hi == 0) {
                const float s4 = oE[4] + oO[4], s5 = oE[5] + oO[5];
                const float s6 = oE[6] + oO[6], s7 = oE[7] + oO[7];
                *(float4*)(orow + 0) = make_float4(s0 + b2A.x, s1 + b2A.y,
                                                   s2 + b2A.z, s3 + b2A.w);
                *(float4*)(orow + 8) = make_float4(s4 + b2B.x, s5 + b2B.y,
                                                   s6 + b2B.z, s7 + b2B.w);
            } else {
                *(float4*)(orow + 4) = make_float4(s0 + b2A.x, s1 + b2A.y,
                                                   s2 + b2A.z, s3 + b2A.w);
            }
        }

        if (!haveN) break;
        fa = fa2; fb = fb2; fc = fc2; p = p2; c = cn;
    }
}

// ---------------------------------------------------------------------------
extern "C" void kernel_launch(void* const* d_in, const int* in_sizes, int n_in,
                              void* d_out, int out_size, void* d_ws, size_t ws_size,
                              hipStream_t stream) {
    const float* mixer_x    = (const float*)d_in[0];
    const float* features   = (const float*)d_in[1];
    const float* W1         = (const float*)d_in[2];
    const float* b1         = (const float*)d_in[3];
    const float* W2         = (const float*)d_in[4];
    const float* b2         = (const float*)d_in[5];
    const int*   node_patch = (const int*)d_in[6];
    float* out = (float*)d_out;

    unsigned short* patch_t = (unsigned short*)d_ws;           // 118784 B
    u32x4*          wfrag   = (u32x4*)((char*)d_ws + 118784);  // +20480 B

    precompute<<<257, 1024, 0, stream>>>(mixer_x, W1, b1, W2, patch_t, wfrag);

    node_mlp_mfma<<<256, K2_THREADS, 0, stream>>>(features, node_patch,
                                                  patch_t, wfrag, b2, out);
}